// Round 17
// baseline (596.399 us; speedup 1.0000x reference)
//
#include <hip/hip_runtime.h>

// RNN_53214644797476: out = tanh(X @ W^T + hs @ H^T), hs never updated.
// => one GEMM [32768,1024]x[1024,1024]^T + tiny h_term + tanh epilogue.
// Round 17: R16 verbatim EXCEPT: 2 LDS buffers (48 KB) instead of 3 ->
// 3 blocks/CU x 8 waves = 24 waves/CU (every config at <16 waves lost;
// >16 never tested; TLP is the measured stall-hiding mechanism here).
// 1-deep prefetch (stage kt+1 at top into buf^1, vmcnt(0)+barrier at end;
// R9-proven WAR-safe). __launch_bounds__(512,6) caps VGPR at 84 (need 60).
// Keeps R16's transpose epilogue (WRITE 131 MB, full-line nt stores),
// pre-swizzled inputs (0 K-loop conflicts), XCD-bijective swizzle.

typedef __bf16 bf16x8 __attribute__((ext_vector_type(8)));
typedef float f32x4 __attribute__((ext_vector_type(4)));
typedef unsigned short us8 __attribute__((ext_vector_type(8)));

constexpr int M_TOT = 32768;  // SEQ*BATCH
constexpr int K_D = 1024;
constexpr int N_D = 1024;
constexpr int BM = 256, BN = 128, BKT = 32;
constexpr int NTK = K_D / BKT;  // 32 K-tiles
constexpr int ATILE = BM * BKT; // 8192 ushorts = 16 KiB
constexpr int BTILE = BN * BKT; // 4096 ushorts = 8 KiB

__device__ __forceinline__ void async16(const void* g, void* l) {
  __builtin_amdgcn_global_load_lds(
      (const __attribute__((address_space(1))) unsigned int*)g,
      (__attribute__((address_space(3))) unsigned int*)l, 16, 0, 0);
}

__device__ __forceinline__ unsigned short f2bf(float f) {
  unsigned int u = __float_as_uint(f);
  u += 0x7FFFu + ((u >> 16) & 1u);  // round-to-nearest-even
  return (unsigned short)(u >> 16);
}

// ---- merged prep (identical to R14-R16) ----
constexpr int PREP_XBLK = M_TOT * K_D / 8 / 256;  // 16384
constexpr int PREP_WBLK = N_D * K_D / 8 / 256;    // 512
constexpr int PREP_HBLK = 1024;
constexpr int PREP_GRID = PREP_XBLK + PREP_WBLK + PREP_HBLK;

__global__ __launch_bounds__(256) void prep_kernel(
    const float* __restrict__ X, unsigned short* __restrict__ Xbf,
    const float* __restrict__ W, unsigned short* __restrict__ Wbf,
    const float* __restrict__ hs, const float* __restrict__ Hm,
    float* __restrict__ ht) {
  __shared__ float4 Hrow4[256];
  const int b = blockIdx.x;
  const int tid = threadIdx.x;

  if (b < PREP_XBLK + PREP_WBLK) {
    const float* in = (b < PREP_XBLK) ? X : W;
    unsigned short* out = (b < PREP_XBLK) ? Xbf : Wbf;
    int j = (b < PREP_XBLK) ? (b * 256 + tid) : ((b - PREP_XBLK) * 256 + tid);
    // j indexes full 16B slots (8 floats each).
    int row = j >> 7, st = j & 127;
    int sd = (st & ~3) | ((st & 3) ^ ((row >> 1) & 3));
    const f32x4* p = reinterpret_cast<const f32x4*>(in + (size_t)j * 8);
    f32x4 a = __builtin_nontemporal_load(p);      // read-once stream: nt
    f32x4 c = __builtin_nontemporal_load(p + 1);  // 2 independent loads
    us8 v;
    v[0] = f2bf(a[0]); v[1] = f2bf(a[1]); v[2] = f2bf(a[2]); v[3] = f2bf(a[3]);
    v[4] = f2bf(c[0]); v[5] = f2bf(c[1]); v[6] = f2bf(c[2]); v[7] = f2bf(c[3]);
    *reinterpret_cast<us8*>(out + (size_t)row * 1024 + sd * 8) = v;
  } else {
    // h_term[bb][h] = sum_k hs[bb][k] * Hm[h][k]
    int h = b - (PREP_XBLK + PREP_WBLK);
    Hrow4[tid] = reinterpret_cast<const float4*>(Hm + (size_t)h * 1024)[tid];
    __syncthreads();
    int w = tid >> 6, l = tid & 63;
#pragma unroll 2
    for (int bb = w * 16; bb < w * 16 + 16; ++bb) {
      const float4* hb4 = reinterpret_cast<const float4*>(hs + (size_t)bb * 1024);
      float s = 0.f;
#pragma unroll
      for (int p = 0; p < 4; ++p) {
        float4 x = hb4[l + p * 64];
        float4 y = Hrow4[l + p * 64];
        s += x.x * y.x + x.y * y.y + x.z * y.z + x.w * y.w;
      }
#pragma unroll
      for (int off = 32; off > 0; off >>= 1) s += __shfl_down(s, off, 64);
      if (l == 0) ht[bb * 1024 + h] = s;
    }
  }
}

// ---- main GEMM: C = tanh(A.B^T + ht[m%64][n]) ----
// 256x128 tile, 8 waves (4x2) of 64x64, 2-buffer 1-deep, 3 blocks/CU.
__global__ __launch_bounds__(512, 6) void gemm_tanh(
    const unsigned short* __restrict__ A, const unsigned short* __restrict__ B,
    const float* __restrict__ ht, float* __restrict__ out0,
    float* __restrict__ out1) {
  __shared__ unsigned short As[2][ATILE];  // 32 KiB
  __shared__ unsigned short Bs[2][BTILE];  // 16 KiB

  // XCD-bijective swizzle (nwg = 1024 % 8 == 0); A-panel sharers co-XCD.
  int bid = blockIdx.x;
  int swz = (bid & 7) * 128 + (bid >> 3);
  int bm = swz >> 3;  // 0..127
  int bn = swz & 7;   // 0..7

  int tid = threadIdx.x;
  int lane = tid & 63, wid = tid >> 6;
  int wr = wid >> 1, wc = wid & 1;  // 4 x 2 waves, each 64x64 output
  int fr = lane & 15, kq = lane >> 4;

  // Staging: A = 1024 chunks (256 rows x 4 slots), B = 512 chunks.
  // Thread t stages A chunks t, t+512 and B chunk t. LDS dest linear;
  // global source pre-swizzled, so source addrs are linear too.
  int c1 = tid + 512;
  const unsigned short* gA0 =
      A + (size_t)(bm * BM + (tid >> 2)) * 1024 + (tid & 3) * 8;
  const unsigned short* gA1 =
      A + (size_t)(bm * BM + (c1 >> 2)) * 1024 + (tid & 3) * 8;
  const unsigned short* gB0 =
      B + (size_t)(bn * BN + (tid >> 2)) * 1024 + (tid & 3) * 8;

  f32x4 acc[4][4] = {};

#define STAGE(kt, buf)                                  \
  {                                                     \
    async16(gA0 + (kt) * BKT, &As[buf][tid * 8]);       \
    async16(gA1 + (kt) * BKT, &As[buf][c1 * 8]);        \
    async16(gB0 + (kt) * BKT, &Bs[buf][tid * 8]);       \
  }

  // Prologue: stage tile 0; drain; barrier.
  STAGE(0, 0);
  asm volatile("s_waitcnt vmcnt(0)" ::: "memory");
  __builtin_amdgcn_s_barrier();
  asm volatile("" ::: "memory");

  for (int kt = 0; kt < NTK; ++kt) {
    const int cur = kt & 1;
    // Stage next tile into the other buffer; flies during ds_read + MFMA.
    if (kt + 1 < NTK) STAGE(kt + 1, cur ^ 1);

    bf16x8 af[4], bg[4];
#pragma unroll
    for (int mi = 0; mi < 4; ++mi) {
      int ra = wr * 64 + mi * 16 + fr;
      af[mi] = *reinterpret_cast<const bf16x8*>(
          &As[cur][ra * BKT + (kq ^ ((ra >> 1) & 3)) * 8]);
    }
#pragma unroll
    for (int ni = 0; ni < 4; ++ni) {
      int rb = wc * 64 + ni * 16 + fr;
      bg[ni] = *reinterpret_cast<const bf16x8*>(
          &Bs[cur][rb * BKT + (kq ^ ((rb >> 1) & 3)) * 8]);
    }
    __builtin_amdgcn_s_setprio(1);
#pragma unroll
    for (int mi = 0; mi < 4; ++mi)
#pragma unroll
      for (int ni = 0; ni < 4; ++ni)
        acc[mi][ni] = __builtin_amdgcn_mfma_f32_16x16x32_bf16(
            af[mi], bg[ni], acc[mi][ni], 0, 0, 0);
    __builtin_amdgcn_s_setprio(0);

    if (kt + 1 < NTK) {
      // Next tile must be resident for everyone; the drain stall is
      // covered by the other 2 resident blocks on this CU (24 waves).
      asm volatile("s_waitcnt vmcnt(0)" ::: "memory");
      __builtin_amdgcn_s_barrier();
      asm volatile("" ::: "memory");
    }
  }

  // ---- Epilogue: per-wave LDS transpose -> full-line nt stores ----
  // All waves done reading As/Bs before we reuse the LDS.
  __builtin_amdgcn_s_barrier();

  // Private 4 KB (1024 f32) region per wave inside As (8 x 4 KB = 32 KB).
  float* eps = reinterpret_cast<float*>(&As[0][0]) + wid * 1024;
  const int nbase = bn * BN + wc * 64;
  const int mwave = bm * BM + wr * 64;

#pragma unroll
  for (int mi = 0; mi < 4; ++mi) {
    // 1. compute y, scatter into LDS transposed+swizzled.
#pragma unroll
    for (int r = 0; r < 4; ++r) {
      int row_rel = kq * 4 + r;
#pragma unroll
      for (int ni = 0; ni < 4; ++ni) {
        int n = nbase + ni * 16 + fr;
        float x = acc[mi][ni][r] + ht[(mi * 16 + row_rel) * 1024 + n];
        float e = __expf(2.0f * x);
        float y = 1.0f - 2.0f / (e + 1.0f);  // tanh(x), safe at +-inf
        int colws = (ni * 16 + fr) ^ (kq * 8) ^ (r * 4);
        eps[row_rel * 64 + colws] = y;
      }
    }
    // 2. gather 4 rows per b128 read (same-key XOR), nt-store full float4s.
#pragma unroll
    for (int i = 0; i < 4; ++i) {
      int rrel = (lane & 3) + 4 * i;
      int colw = 4 * (lane >> 2);
      int colws = colw ^ (i * 8) ^ ((lane & 3) * 4);
      f32x4 v4 = *reinterpret_cast<const f32x4*>(&eps[rrel * 64 + colws]);
      size_t m = (size_t)mwave + mi * 16 + rrel;
      int n = nbase + colw;
      __builtin_nontemporal_store(
          v4, reinterpret_cast<f32x4*>(&out0[m * 1024 + n]));
      if (m >= (size_t)(M_TOT - 64))
        __builtin_nontemporal_store(
            v4, reinterpret_cast<f32x4*>(&out1[(m - (M_TOT - 64)) * 1024 + n]));
    }
  }
#undef STAGE
}

extern "C" void kernel_launch(void* const* d_in, const int* in_sizes, int n_in,
                              void* d_out, int out_size, void* d_ws,
                              size_t ws_size, hipStream_t stream) {
  (void)in_sizes; (void)n_in; (void)out_size; (void)ws_size;
  const float* X  = (const float*)d_in[0];  // [512,64,1024] = [32768,1024]
  const float* hs = (const float*)d_in[1];  // [64,1024]
  const float* W  = (const float*)d_in[2];  // [1024,1024]
  const float* Hm = (const float*)d_in[3];  // [1024,1024]
  float* out0 = (float*)d_out;               // [32768,1024]
  float* out1 = out0 + (size_t)M_TOT * N_D;  // [64,1024]

  // ws layout: Xbf (64 MiB) | Wbf (2 MiB) | hterm (256 KiB)
  unsigned short* Xbf = (unsigned short*)d_ws;
  unsigned short* Wbf = Xbf + (size_t)M_TOT * K_D;
  float* hterm = (float*)(Wbf + (size_t)N_D * K_D);

  prep_kernel<<<PREP_GRID, 256, 0, stream>>>(X, Xbf, W, Wbf, hs, Hm, hterm);
  gemm_tanh<<<(M_TOT / BM) * (N_D / BN), 512, 0, stream>>>(Xbf, Wbf, hterm,
                                                           out0, out1);
}

// Round 18
// 143.843 us; speedup vs baseline: 4.1462x; 4.1462x over previous
//
#include <hip/hip_runtime.h>

// RNN_53214644797476: out = tanh(X @ W^T + hs @ H^T), hs never updated.
// => one GEMM [32768,1024]x[1024,1024]^T + tiny h_term + tanh epilogue.
// Round 18: R17's 24-wave/CU experiment done RIGHT. R17's 596us disaster
// was __launch_bounds__(512,6): min 6 waves/SIMD capped VGPR at 40 < the
// 64 the accumulator needs -> total spill (WRITE_SIZE 1.5 GB = scratch).
// Fix: __launch_bounds__(512,4) (VGPR budget 128; kernel naturally uses
// ~60 <= 64, which HW-permits 8 waves/SIMD anyway). LDS 48 KB (2 buffers)
// is then the binding constraint -> 3 blocks/CU x 8 waves = 24 waves/CU.
// Everything else identical to R16/R17: 256x128 tile, BK=32, 1-deep dbuf
// (stage kt+1 at top, vmcnt(0)+barrier at end), pre-swizzled inputs,
// XCD-bijective swizzle, transpose epilogue with full-line nt stores.

typedef __bf16 bf16x8 __attribute__((ext_vector_type(8)));
typedef float f32x4 __attribute__((ext_vector_type(4)));
typedef unsigned short us8 __attribute__((ext_vector_type(8)));

constexpr int M_TOT = 32768;  // SEQ*BATCH
constexpr int K_D = 1024;
constexpr int N_D = 1024;
constexpr int BM = 256, BN = 128, BKT = 32;
constexpr int NTK = K_D / BKT;  // 32 K-tiles
constexpr int ATILE = BM * BKT; // 8192 ushorts = 16 KiB
constexpr int BTILE = BN * BKT; // 4096 ushorts = 8 KiB

__device__ __forceinline__ void async16(const void* g, void* l) {
  __builtin_amdgcn_global_load_lds(
      (const __attribute__((address_space(1))) unsigned int*)g,
      (__attribute__((address_space(3))) unsigned int*)l, 16, 0, 0);
}

__device__ __forceinline__ unsigned short f2bf(float f) {
  unsigned int u = __float_as_uint(f);
  u += 0x7FFFu + ((u >> 16) & 1u);  // round-to-nearest-even
  return (unsigned short)(u >> 16);
}

// ---- merged prep (identical to R14-R17) ----
constexpr int PREP_XBLK = M_TOT * K_D / 8 / 256;  // 16384
constexpr int PREP_WBLK = N_D * K_D / 8 / 256;    // 512
constexpr int PREP_HBLK = 1024;
constexpr int PREP_GRID = PREP_XBLK + PREP_WBLK + PREP_HBLK;

__global__ __launch_bounds__(256) void prep_kernel(
    const float* __restrict__ X, unsigned short* __restrict__ Xbf,
    const float* __restrict__ W, unsigned short* __restrict__ Wbf,
    const float* __restrict__ hs, const float* __restrict__ Hm,
    float* __restrict__ ht) {
  __shared__ float4 Hrow4[256];
  const int b = blockIdx.x;
  const int tid = threadIdx.x;

  if (b < PREP_XBLK + PREP_WBLK) {
    const float* in = (b < PREP_XBLK) ? X : W;
    unsigned short* out = (b < PREP_XBLK) ? Xbf : Wbf;
    int j = (b < PREP_XBLK) ? (b * 256 + tid) : ((b - PREP_XBLK) * 256 + tid);
    // j indexes full 16B slots (8 floats each).
    int row = j >> 7, st = j & 127;
    int sd = (st & ~3) | ((st & 3) ^ ((row >> 1) & 3));
    const f32x4* p = reinterpret_cast<const f32x4*>(in + (size_t)j * 8);
    f32x4 a = __builtin_nontemporal_load(p);      // read-once stream: nt
    f32x4 c = __builtin_nontemporal_load(p + 1);  // 2 independent loads
    us8 v;
    v[0] = f2bf(a[0]); v[1] = f2bf(a[1]); v[2] = f2bf(a[2]); v[3] = f2bf(a[3]);
    v[4] = f2bf(c[0]); v[5] = f2bf(c[1]); v[6] = f2bf(c[2]); v[7] = f2bf(c[3]);
    *reinterpret_cast<us8*>(out + (size_t)row * 1024 + sd * 8) = v;
  } else {
    // h_term[bb][h] = sum_k hs[bb][k] * Hm[h][k]
    int h = b - (PREP_XBLK + PREP_WBLK);
    Hrow4[tid] = reinterpret_cast<const float4*>(Hm + (size_t)h * 1024)[tid];
    __syncthreads();
    int w = tid >> 6, l = tid & 63;
#pragma unroll 2
    for (int bb = w * 16; bb < w * 16 + 16; ++bb) {
      const float4* hb4 = reinterpret_cast<const float4*>(hs + (size_t)bb * 1024);
      float s = 0.f;
#pragma unroll
      for (int p = 0; p < 4; ++p) {
        float4 x = hb4[l + p * 64];
        float4 y = Hrow4[l + p * 64];
        s += x.x * y.x + x.y * y.y + x.z * y.z + x.w * y.w;
      }
#pragma unroll
      for (int off = 32; off > 0; off >>= 1) s += __shfl_down(s, off, 64);
      if (l == 0) ht[bb * 1024 + h] = s;
    }
  }
}

// ---- main GEMM: C = tanh(A.B^T + ht[m%64][n]) ----
// 256x128 tile, 8 waves (4x2) of 64x64, 2-buffer 1-deep, 3 blocks/CU.
__global__ __launch_bounds__(512, 4) void gemm_tanh(
    const unsigned short* __restrict__ A, const unsigned short* __restrict__ B,
    const float* __restrict__ ht, float* __restrict__ out0,
    float* __restrict__ out1) {
  __shared__ unsigned short As[2][ATILE];  // 32 KiB
  __shared__ unsigned short Bs[2][BTILE];  // 16 KiB

  // XCD-bijective swizzle (nwg = 1024 % 8 == 0); A-panel sharers co-XCD.
  int bid = blockIdx.x;
  int swz = (bid & 7) * 128 + (bid >> 3);
  int bm = swz >> 3;  // 0..127
  int bn = swz & 7;   // 0..7

  int tid = threadIdx.x;
  int lane = tid & 63, wid = tid >> 6;
  int wr = wid >> 1, wc = wid & 1;  // 4 x 2 waves, each 64x64 output
  int fr = lane & 15, kq = lane >> 4;

  // Staging: A = 1024 chunks (256 rows x 4 slots), B = 512 chunks.
  // Thread t stages A chunks t, t+512 and B chunk t. LDS dest linear;
  // global source pre-swizzled, so source addrs are linear too.
  int c1 = tid + 512;
  const unsigned short* gA0 =
      A + (size_t)(bm * BM + (tid >> 2)) * 1024 + (tid & 3) * 8;
  const unsigned short* gA1 =
      A + (size_t)(bm * BM + (c1 >> 2)) * 1024 + (tid & 3) * 8;
  const unsigned short* gB0 =
      B + (size_t)(bn * BN + (tid >> 2)) * 1024 + (tid & 3) * 8;

  f32x4 acc[4][4] = {};

#define STAGE(kt, buf)                                  \
  {                                                     \
    async16(gA0 + (kt) * BKT, &As[buf][tid * 8]);       \
    async16(gA1 + (kt) * BKT, &As[buf][c1 * 8]);        \
    async16(gB0 + (kt) * BKT, &Bs[buf][tid * 8]);       \
  }

  // Prologue: stage tile 0; drain; barrier.
  STAGE(0, 0);
  asm volatile("s_waitcnt vmcnt(0)" ::: "memory");
  __builtin_amdgcn_s_barrier();
  asm volatile("" ::: "memory");

  for (int kt = 0; kt < NTK; ++kt) {
    const int cur = kt & 1;
    // Stage next tile into the other buffer; flies during ds_read + MFMA.
    if (kt + 1 < NTK) STAGE(kt + 1, cur ^ 1);

    bf16x8 af[4], bg[4];
#pragma unroll
    for (int mi = 0; mi < 4; ++mi) {
      int ra = wr * 64 + mi * 16 + fr;
      af[mi] = *reinterpret_cast<const bf16x8*>(
          &As[cur][ra * BKT + (kq ^ ((ra >> 1) & 3)) * 8]);
    }
#pragma unroll
    for (int ni = 0; ni < 4; ++ni) {
      int rb = wc * 64 + ni * 16 + fr;
      bg[ni] = *reinterpret_cast<const bf16x8*>(
          &Bs[cur][rb * BKT + (kq ^ ((rb >> 1) & 3)) * 8]);
    }
    __builtin_amdgcn_s_setprio(1);
#pragma unroll
    for (int mi = 0; mi < 4; ++mi)
#pragma unroll
      for (int ni = 0; ni < 4; ++ni)
        acc[mi][ni] = __builtin_amdgcn_mfma_f32_16x16x32_bf16(
            af[mi], bg[ni], acc[mi][ni], 0, 0, 0);
    __builtin_amdgcn_s_setprio(0);

    if (kt + 1 < NTK) {
      // Next tile must be resident for everyone; the drain stall is
      // covered by the other 2 resident blocks on this CU (24 waves).
      asm volatile("s_waitcnt vmcnt(0)" ::: "memory");
      __builtin_amdgcn_s_barrier();
      asm volatile("" ::: "memory");
    }
  }

  // ---- Epilogue: per-wave LDS transpose -> full-line nt stores ----
  // All waves done reading As/Bs before we reuse the LDS.
  __builtin_amdgcn_s_barrier();

  // Private 4 KB (1024 f32) region per wave inside As (8 x 4 KB = 32 KB).
  float* eps = reinterpret_cast<float*>(&As[0][0]) + wid * 1024;
  const int nbase = bn * BN + wc * 64;
  const int mwave = bm * BM + wr * 64;

#pragma unroll
  for (int mi = 0; mi < 4; ++mi) {
    // 1. compute y, scatter into LDS transposed+swizzled.
#pragma unroll
    for (int r = 0; r < 4; ++r) {
      int row_rel = kq * 4 + r;
#pragma unroll
      for (int ni = 0; ni < 4; ++ni) {
        int n = nbase + ni * 16 + fr;
        float x = acc[mi][ni][r] + ht[(mi * 16 + row_rel) * 1024 + n];
        float e = __expf(2.0f * x);
        float y = 1.0f - 2.0f / (e + 1.0f);  // tanh(x), safe at +-inf
        int colws = (ni * 16 + fr) ^ (kq * 8) ^ (r * 4);
        eps[row_rel * 64 + colws] = y;
      }
    }
    // 2. gather 4 rows per b128 read (same-key XOR), nt-store full float4s.
#pragma unroll
    for (int i = 0; i < 4; ++i) {
      int rrel = (lane & 3) + 4 * i;
      int colw = 4 * (lane >> 2);
      int colws = colw ^ (i * 8) ^ ((lane & 3) * 4);
      f32x4 v4 = *reinterpret_cast<const f32x4*>(&eps[rrel * 64 + colws]);
      size_t m = (size_t)mwave + mi * 16 + rrel;
      int n = nbase + colw;
      __builtin_nontemporal_store(
          v4, reinterpret_cast<f32x4*>(&out0[m * 1024 + n]));
      if (m >= (size_t)(M_TOT - 64))
        __builtin_nontemporal_store(
            v4, reinterpret_cast<f32x4*>(&out1[(m - (M_TOT - 64)) * 1024 + n]));
    }
  }
#undef STAGE
}

extern "C" void kernel_launch(void* const* d_in, const int* in_sizes, int n_in,
                              void* d_out, int out_size, void* d_ws,
                              size_t ws_size, hipStream_t stream) {
  (void)in_sizes; (void)n_in; (void)out_size; (void)ws_size;
  const float* X  = (const float*)d_in[0];  // [512,64,1024] = [32768,1024]
  const float* hs = (const float*)d_in[1];  // [64,1024]
  const float* W  = (const float*)d_in[2];  // [1024,1024]
  const float* Hm = (const float*)d_in[3];  // [1024,1024]
  float* out0 = (float*)d_out;               // [32768,1024]
  float* out1 = out0 + (size_t)M_TOT * N_D;  // [64,1024]

  // ws layout: Xbf (64 MiB) | Wbf (2 MiB) | hterm (256 KiB)
  unsigned short* Xbf = (unsigned short*)d_ws;
  unsigned short* Wbf = Xbf + (size_t)M_TOT * K_D;
  float* hterm = (float*)(Wbf + (size_t)N_D * K_D);

  prep_kernel<<<PREP_GRID, 256, 0, stream>>>(X, Xbf, W, Wbf, hs, Hm, hterm);
  gemm_tanh<<<(M_TOT / BM) * (N_D / BN), 512, 0, stream>>>(Xbf, Wbf, hterm,
                                                           out0, out1);
}

// Round 19
// 139.264 us; speedup vs baseline: 4.2825x; 1.0329x over previous
//
#include <hip/hip_runtime.h>

// RNN_53214644797476: out = tanh(X @ W^T + hs @ H^T), hs never updated.
// => one GEMM [32768,1024]x[1024,1024]^T + tiny h_term + tanh epilogue.
// Round 19 (FINAL = R16, the measured best at 139.88 us):
//  prep: merged cvtX/cvtW/hterm, 1 work-item/thread, nt f32 loads,
//        4-slot pre-swizzle (sd = (st&~3)|((st&3)^((row>>1)&3))).
//  gemm: 256x128 tile, 512 thr, 8 waves 64x64, BK=32, 3-buffer 2-deep
//        counted-vmcnt(3) pipeline (never 0 in-loop), 72 KB LDS ->
//        2 blk/CU x 8 waves = 16 waves/CU (measured optimum), gload_lds
//        linear dest + XOR ds_read (0 K-loop bank conflicts), setprio
//        around MFMA, XCD-bijective swizzle, per-wave LDS-transpose
//        epilogue -> full-line nt dwordx4 stores (WRITE exactly 131 MB).
// Axis map (18 rounds): 8-phase x2, fusion x2, BK=64, B-direct, 1-deep,
// 24-wave, 12-wave all falsified; this config best on every axis.

typedef __bf16 bf16x8 __attribute__((ext_vector_type(8)));
typedef float f32x4 __attribute__((ext_vector_type(4)));
typedef unsigned short us8 __attribute__((ext_vector_type(8)));

constexpr int M_TOT = 32768;  // SEQ*BATCH
constexpr int K_D = 1024;
constexpr int N_D = 1024;
constexpr int BM = 256, BN = 128, BKT = 32;
constexpr int NTK = K_D / BKT;  // 32 K-tiles
constexpr int ATILE = BM * BKT; // 8192 ushorts = 16 KiB
constexpr int BTILE = BN * BKT; // 4096 ushorts = 8 KiB

__device__ __forceinline__ void async16(const void* g, void* l) {
  __builtin_amdgcn_global_load_lds(
      (const __attribute__((address_space(1))) unsigned int*)g,
      (__attribute__((address_space(3))) unsigned int*)l, 16, 0, 0);
}

__device__ __forceinline__ unsigned short f2bf(float f) {
  unsigned int u = __float_as_uint(f);
  u += 0x7FFFu + ((u >> 16) & 1u);  // round-to-nearest-even
  return (unsigned short)(u >> 16);
}

// ---- merged prep ----
constexpr int PREP_XBLK = M_TOT * K_D / 8 / 256;  // 16384
constexpr int PREP_WBLK = N_D * K_D / 8 / 256;    // 512
constexpr int PREP_HBLK = 1024;
constexpr int PREP_GRID = PREP_XBLK + PREP_WBLK + PREP_HBLK;

__global__ __launch_bounds__(256) void prep_kernel(
    const float* __restrict__ X, unsigned short* __restrict__ Xbf,
    const float* __restrict__ W, unsigned short* __restrict__ Wbf,
    const float* __restrict__ hs, const float* __restrict__ Hm,
    float* __restrict__ ht) {
  __shared__ float4 Hrow4[256];
  const int b = blockIdx.x;
  const int tid = threadIdx.x;

  if (b < PREP_XBLK + PREP_WBLK) {
    const float* in = (b < PREP_XBLK) ? X : W;
    unsigned short* out = (b < PREP_XBLK) ? Xbf : Wbf;
    int j = (b < PREP_XBLK) ? (b * 256 + tid) : ((b - PREP_XBLK) * 256 + tid);
    // j indexes full 16B slots (8 floats each).
    int row = j >> 7, st = j & 127;
    int sd = (st & ~3) | ((st & 3) ^ ((row >> 1) & 3));
    const f32x4* p = reinterpret_cast<const f32x4*>(in + (size_t)j * 8);
    f32x4 a = __builtin_nontemporal_load(p);      // read-once stream: nt
    f32x4 c = __builtin_nontemporal_load(p + 1);  // 2 independent loads
    us8 v;
    v[0] = f2bf(a[0]); v[1] = f2bf(a[1]); v[2] = f2bf(a[2]); v[3] = f2bf(a[3]);
    v[4] = f2bf(c[0]); v[5] = f2bf(c[1]); v[6] = f2bf(c[2]); v[7] = f2bf(c[3]);
    *reinterpret_cast<us8*>(out + (size_t)row * 1024 + sd * 8) = v;
  } else {
    // h_term[bb][h] = sum_k hs[bb][k] * Hm[h][k]
    int h = b - (PREP_XBLK + PREP_WBLK);
    Hrow4[tid] = reinterpret_cast<const float4*>(Hm + (size_t)h * 1024)[tid];
    __syncthreads();
    int w = tid >> 6, l = tid & 63;
#pragma unroll 2
    for (int bb = w * 16; bb < w * 16 + 16; ++bb) {
      const float4* hb4 = reinterpret_cast<const float4*>(hs + (size_t)bb * 1024);
      float s = 0.f;
#pragma unroll
      for (int p = 0; p < 4; ++p) {
        float4 x = hb4[l + p * 64];
        float4 y = Hrow4[l + p * 64];
        s += x.x * y.x + x.y * y.y + x.z * y.z + x.w * y.w;
      }
#pragma unroll
      for (int off = 32; off > 0; off >>= 1) s += __shfl_down(s, off, 64);
      if (l == 0) ht[bb * 1024 + h] = s;
    }
  }
}

// ---- main GEMM: C = tanh(A.B^T + ht[m%64][n]) ----
// 256x128 tile, 8 waves (4x2) of 64x64, 3-buffer 2-deep counted-vmcnt.
// Epilogue: per-wave LDS transpose -> full-line nt dwordx4 stores.
__global__ __launch_bounds__(512, 4) void gemm_tanh(
    const unsigned short* __restrict__ A, const unsigned short* __restrict__ B,
    const float* __restrict__ ht, float* __restrict__ out0,
    float* __restrict__ out1) {
  __shared__ unsigned short As[3][ATILE];  // 48 KiB
  __shared__ unsigned short Bs[3][BTILE];  // 24 KiB

  // XCD-bijective swizzle (nwg = 1024 % 8 == 0); A-panel sharers co-XCD.
  int bid = blockIdx.x;
  int swz = (bid & 7) * 128 + (bid >> 3);
  int bm = swz >> 3;  // 0..127
  int bn = swz & 7;   // 0..7

  int tid = threadIdx.x;
  int lane = tid & 63, wid = tid >> 6;
  int wr = wid >> 1, wc = wid & 1;  // 4 x 2 waves, each 64x64 output
  int fr = lane & 15, kq = lane >> 4;

  // Staging: A = 1024 chunks (256 rows x 4 slots), B = 512 chunks.
  // Thread t stages A chunks t, t+512 and B chunk t. LDS dest linear;
  // global source pre-swizzled, so source addrs are linear too.
  int c1 = tid + 512;
  const unsigned short* gA0 =
      A + (size_t)(bm * BM + (tid >> 2)) * 1024 + (tid & 3) * 8;
  const unsigned short* gA1 =
      A + (size_t)(bm * BM + (c1 >> 2)) * 1024 + (tid & 3) * 8;
  const unsigned short* gB0 =
      B + (size_t)(bn * BN + (tid >> 2)) * 1024 + (tid & 3) * 8;

  f32x4 acc[4][4] = {};

#define STAGE(kt, buf)                                  \
  {                                                     \
    async16(gA0 + (kt) * BKT, &As[buf][tid * 8]);       \
    async16(gA1 + (kt) * BKT, &As[buf][c1 * 8]);        \
    async16(gB0 + (kt) * BKT, &Bs[buf][tid * 8]);       \
  }

  // Prologue: stage tiles 0 and 1; wait tile 0 only (counted); barrier.
  STAGE(0, 0);
  STAGE(1, 1);
  asm volatile("s_waitcnt vmcnt(3)" ::: "memory");
  __builtin_amdgcn_s_barrier();
  asm volatile("" ::: "memory");

  for (int kt = 0; kt < NTK; ++kt) {
    const int cur = kt % 3;
    // Stage 2 K-steps ahead; these loads fly across this iter's barrier.
    if (kt + 2 < NTK) STAGE(kt + 2, (kt + 2) % 3);

    bf16x8 af[4], bg[4];
#pragma unroll
    for (int mi = 0; mi < 4; ++mi) {
      int ra = wr * 64 + mi * 16 + fr;
      af[mi] = *reinterpret_cast<const bf16x8*>(
          &As[cur][ra * BKT + (kq ^ ((ra >> 1) & 3)) * 8]);
    }
#pragma unroll
    for (int ni = 0; ni < 4; ++ni) {
      int rb = wc * 64 + ni * 16 + fr;
      bg[ni] = *reinterpret_cast<const bf16x8*>(
          &Bs[cur][rb * BKT + (kq ^ ((rb >> 1) & 3)) * 8]);
    }
    __builtin_amdgcn_s_setprio(1);
#pragma unroll
    for (int mi = 0; mi < 4; ++mi)
#pragma unroll
      for (int ni = 0; ni < 4; ++ni)
        acc[mi][ni] = __builtin_amdgcn_mfma_f32_16x16x32_bf16(
            af[mi], bg[ni], acc[mi][ni], 0, 0, 0);
    __builtin_amdgcn_s_setprio(0);

    if (kt + 1 < NTK) {
      // Counted drain: ensure kt+1 resident (its 3 loads are the oldest),
      // keep kt+2's 3 loads in flight across the barrier.
      if (kt + 2 < NTK)
        asm volatile("s_waitcnt vmcnt(3)" ::: "memory");
      else
        asm volatile("s_waitcnt vmcnt(0)" ::: "memory");
      __builtin_amdgcn_s_barrier();
      asm volatile("" ::: "memory");
    }
  }

  // ---- Epilogue: per-wave LDS transpose -> full-line nt stores ----
  // All waves done reading As/Bs before we reuse the LDS.
  __builtin_amdgcn_s_barrier();

  // Private 4 KB (1024 f32) region per wave inside As (8 x 4 KB = 32 KB).
  float* eps = reinterpret_cast<float*>(&As[0][0]) + wid * 1024;
  const int nbase = bn * BN + wc * 64;
  const int mwave = bm * BM + wr * 64;

#pragma unroll
  for (int mi = 0; mi < 4; ++mi) {
    // 1. compute y, scatter into LDS transposed+swizzled.
#pragma unroll
    for (int r = 0; r < 4; ++r) {
      int row_rel = kq * 4 + r;
#pragma unroll
      for (int ni = 0; ni < 4; ++ni) {
        int n = nbase + ni * 16 + fr;
        float x = acc[mi][ni][r] + ht[(mi * 16 + row_rel) * 1024 + n];
        float e = __expf(2.0f * x);
        float y = 1.0f - 2.0f / (e + 1.0f);  // tanh(x), safe at +-inf
        int colws = (ni * 16 + fr) ^ (kq * 8) ^ (r * 4);
        eps[row_rel * 64 + colws] = y;
      }
    }
    // 2. gather 4 rows per b128 read (same-key XOR), nt-store full float4s.
#pragma unroll
    for (int i = 0; i < 4; ++i) {
      int rrel = (lane & 3) + 4 * i;
      int colw = 4 * (lane >> 2);
      int colws = colw ^ (i * 8) ^ ((lane & 3) * 4);
      f32x4 v4 = *reinterpret_cast<const f32x4*>(&eps[rrel * 64 + colws]);
      size_t m = (size_t)mwave + mi * 16 + rrel;
      int n = nbase + colw;
      __builtin_nontemporal_store(
          v4, reinterpret_cast<f32x4*>(&out0[m * 1024 + n]));
      if (m >= (size_t)(M_TOT - 64))
        __builtin_nontemporal_store(
            v4, reinterpret_cast<f32x4*>(&out1[(m - (M_TOT - 64)) * 1024 + n]));
    }
  }
#undef STAGE
}

extern "C" void kernel_launch(void* const* d_in, const int* in_sizes, int n_in,
                              void* d_out, int out_size, void* d_ws,
                              size_t ws_size, hipStream_t stream) {
  (void)in_sizes; (void)n_in; (void)out_size; (void)ws_size;
  const float* X  = (const float*)d_in[0];  // [512,64,1024] = [32768,1024]
  const float* hs = (const float*)d_in[1];  // [64,1024]
  const float* W  = (const float*)d_in[2];  // [1024,1024]
  const float* Hm = (const float*)d_in[3];  // [1024,1024]
  float* out0 = (float*)d_out;               // [32768,1024]
  float* out1 = out0 + (size_t)M_TOT * N_D;  // [64,1024]

  // ws layout: Xbf (64 MiB) | Wbf (2 MiB) | hterm (256 KiB)
  unsigned short* Xbf = (unsigned short*)d_ws;
  unsigned short* Wbf = Xbf + (size_t)M_TOT * K_D;
  float* hterm = (float*)(Wbf + (size_t)N_D * K_D);

  prep_kernel<<<PREP_GRID, 256, 0, stream>>>(X, Xbf, W, Wbf, hs, Hm, hterm);
  gemm_tanh<<<(M_TOT / BM) * (N_D / BN), 512, 0, stream>>>(Xbf, Wbf, hterm,
                                                           out0, out1);
}